// Round 3
// baseline (204.296 us; speedup 1.0000x reference)
//
#include <hip/hip_runtime.h>

#define SEQ 2048
#define BATCH 2
#define DM 1024
#define NH 16
#define DH 64

typedef __bf16 bf16;
typedef __bf16 bf16x8 __attribute__((ext_vector_type(8)));
typedef __bf16 bf16x4 __attribute__((ext_vector_type(4)));
typedef float f32x4 __attribute__((ext_vector_type(4)));

#define MFMA16(a, b, c) __builtin_amdgcn_mfma_f32_16x16x32_bf16((a), (b), (c), 0, 0, 0)

#if __has_builtin(__builtin_amdgcn_exp2f)
#define EXP2(x) __builtin_amdgcn_exp2f(x)
#else
#define EXP2(x) exp2f(x)
#endif

// Q scale folds 1/sqrt(64) and log2(e) so softmax uses bare v_exp_f32 (exp2)
#define QSCALE 0.18033688f

// async global->LDS, 16B per lane; LDS dest = wave-uniform base + lane*16
typedef __attribute__((address_space(3))) void lds_void;
typedef __attribute__((address_space(1))) void glb_void;
__device__ __forceinline__ void gld16(void* lds, const void* g) {
    __builtin_amdgcn_global_load_lds((const glb_void*)g, (lds_void*)lds, 16, 0, 0);
}

// swizzled b128 fragment read from a [rows][64] tile (8 chunks of 16B per row)
__device__ __forceinline__ bf16x8 frag64(const bf16* s, int row, int ks, int quad) {
    int phys = (ks * 4 + quad) ^ (row & 7);
    return *(const bf16x8*)&s[row * 64 + phys * 8];
}

// ---------------------------------------------------------------------------
// K0a: cast x (fp32 [4096][1024]) -> bf16
// ---------------------------------------------------------------------------
__global__ __launch_bounds__(256) void k_cast_x(const float* __restrict__ x,
                                                bf16* __restrict__ xb) {
    int t = blockIdx.x * 256 + threadIdx.x;
    const float4* x4 = (const float4*)x;
    float4 a = x4[2 * t];
    float4 b = x4[2 * t + 1];
    bf16x8 o;
    o[0] = (bf16)a.x; o[1] = (bf16)a.y; o[2] = (bf16)a.z; o[3] = (bf16)a.w;
    o[4] = (bf16)b.x; o[5] = (bf16)b.y; o[6] = (bf16)b.z; o[7] = (bf16)b.w;
    *(bf16x8*)(xb + 8 * t) = o;
}

// ---------------------------------------------------------------------------
// K0b: transpose W_{Q,K,V} [h][k=1024][e=64] fp32 -> wT [p][h][e][k] bf16
// ---------------------------------------------------------------------------
__global__ __launch_bounds__(256) void k_trans_qkv(const float* __restrict__ WQ,
                                                   const float* __restrict__ WK,
                                                   const float* __restrict__ WV,
                                                   bf16* __restrict__ wT) {
    int kt = blockIdx.x;
    int ph = blockIdx.y;
    int p = ph >> 4, h = ph & 15;
    const float* Wp = (p == 0) ? WQ : (p == 1) ? WK : WV;
    const float* src = Wp + ((size_t)h * DM + (size_t)kt * 64) * DH;
    __shared__ bf16 T[64 * 65];
    int t = threadIdx.x;
    for (int i = 0; i < 4; i++) {
        int c = t + 256 * i;
        int r = c >> 4;
        int col = (c & 15) * 4;
        float4 v = *(const float4*)&src[r * 64 + col];
        T[(col + 0) * 65 + r] = (bf16)v.x;
        T[(col + 1) * 65 + r] = (bf16)v.y;
        T[(col + 2) * 65 + r] = (bf16)v.z;
        T[(col + 3) * 65 + r] = (bf16)v.w;
    }
    __syncthreads();
    bf16* dst = wT + (size_t)ph * 64 * DM + (size_t)kt * 64;
    for (int i = 0; i < 2; i++) {
        int c = t + 256 * i;
        int e = c >> 3;
        int k0 = (c & 7) * 8;
        bf16x8 o;
        for (int j = 0; j < 8; j++) o[j] = T[e * 65 + k0 + j];
        *(bf16x8*)&dst[(size_t)e * DM + k0] = o;
    }
}

// ---------------------------------------------------------------------------
// K0c: transpose W_O [he=1024][d=1024] fp32 -> woT [d][he] bf16
// ---------------------------------------------------------------------------
__global__ __launch_bounds__(256) void k_trans_wo(const float* __restrict__ WO,
                                                  bf16* __restrict__ woT) {
    int ht = blockIdx.x;
    int dt = blockIdx.y;
    __shared__ bf16 T[64 * 65];
    int t = threadIdx.x;
    for (int i = 0; i < 4; i++) {
        int c = t + 256 * i;
        int r = c >> 4;
        int col = (c & 15) * 4;
        float4 v = *(const float4*)&WO[((size_t)(ht * 64 + r)) * DM + dt * 64 + col];
        T[(col + 0) * 65 + r] = (bf16)v.x;
        T[(col + 1) * 65 + r] = (bf16)v.y;
        T[(col + 2) * 65 + r] = (bf16)v.z;
        T[(col + 3) * 65 + r] = (bf16)v.w;
    }
    __syncthreads();
    for (int i = 0; i < 2; i++) {
        int c = t + 256 * i;
        int d = c >> 3;
        int h0 = (c & 7) * 8;
        bf16x8 o;
        for (int j = 0; j < 8; j++) o[j] = T[d * 65 + h0 + j];
        *(bf16x8*)&woT[((size_t)(dt * 64 + d)) * DM + ht * 64 + h0] = o;
    }
}

// ---------------------------------------------------------------------------
// K1: QKV projection, m97-style staging (gld16 + swizzle).
// p<2 (Q,K): acc = W(A) x X(B) -> m=he, n=s -> packed b64 stores to [s][e].
// p==2 (V):  acc = X(A) x W(B) -> m=s, n=he -> packed b64 stores to VT [e][s].
// grid (32 mt, 8 nt, 3 p), 256 thr.
// ---------------------------------------------------------------------------
__global__ __launch_bounds__(256, 4) void k_qkv(const bf16* __restrict__ xb,
                                                const bf16* __restrict__ wT,
                                                const float* __restrict__ bQ,
                                                const float* __restrict__ bK,
                                                const float* __restrict__ bV,
                                                bf16* __restrict__ Qb,
                                                bf16* __restrict__ Kb,
                                                bf16* __restrict__ VTb) {
    int mt = blockIdx.x, nt = blockIdx.y, p = blockIdx.z;
    __shared__ __align__(16) bf16 Xs[128 * 64];
    __shared__ __align__(16) bf16 Ws[128 * 64];
    int t = threadIdx.x;
    int lane = t & 63, w = t >> 6;
    int l15 = lane & 15, quad = lane >> 4;
    int lrow = lane >> 3, lc = lane & 7;

    const f32x4 z4 = {0.f, 0.f, 0.f, 0.f};
    f32x4 acc[2][8];
    for (int mi = 0; mi < 2; mi++)
        for (int ni = 0; ni < 8; ni++) acc[mi][ni] = z4;

    const bf16* wbase = wT + (size_t)p * 1024 * DM;
    const bf16* sA = (p < 2) ? Ws : Xs;   // A-operand tile
    const bf16* sB = (p < 2) ? Xs : Ws;   // B-operand tile
    int m0 = mt * 128, n0 = nt * 128;

    for (int k0 = 0; k0 < DM; k0 += 64) {
        __syncthreads();
        for (int i = 0; i < 4; i++) {
            int row = w * 32 + i * 8 + lrow;
            int sc = (lc ^ (row & 7)) * 8;
            gld16(&Xs[(w * 32 + i * 8) * 64], xb + (size_t)(m0 + row) * DM + k0 + sc);
            gld16(&Ws[(w * 32 + i * 8) * 64], wbase + (size_t)(n0 + row) * DM + k0 + sc);
        }
        __syncthreads();
        for (int ks = 0; ks < 2; ks++) {
            bf16x8 a0 = frag64(sA, w * 32 + l15, ks, quad);
            bf16x8 a1 = frag64(sA, w * 32 + 16 + l15, ks, quad);
            for (int ni = 0; ni < 8; ni++) {
                bf16x8 bfr = frag64(sB, ni * 16 + l15, ks, quad);
                acc[0][ni] = MFMA16(a0, bfr, acc[0][ni]);
                acc[1][ni] = MFMA16(a1, bfr, acc[1][ni]);
            }
        }
    }

    if (p < 2) {
        const float* bias = (p == 0) ? bQ : bK;
        bf16* dst = (p == 0) ? Qb : Kb;
        float scale = (p == 0) ? QSCALE : 1.0f;
        for (int mi = 0; mi < 2; mi++) {
            int heb = n0 + w * 32 + mi * 16 + quad * 4;   // 4 consecutive he
            float4 b4 = *(const float4*)&bias[heb];
            int h = heb >> 6, e = heb & 63;
            for (int ni = 0; ni < 8; ni++) {
                int s = m0 + ni * 16 + l15;
                int b = s >> 11, si = s & (SEQ - 1);
                bf16x4 o;
                o[0] = (bf16)((acc[mi][ni][0] + b4.x) * scale);
                o[1] = (bf16)((acc[mi][ni][1] + b4.y) * scale);
                o[2] = (bf16)((acc[mi][ni][2] + b4.z) * scale);
                o[3] = (bf16)((acc[mi][ni][3] + b4.w) * scale);
                *(bf16x4*)&dst[((size_t)(b * NH + h) * SEQ + si) * DH + e] = o;
            }
        }
    } else {
        for (int mi = 0; mi < 2; mi++) {
            int sb = m0 + w * 32 + mi * 16 + quad * 4;    // 4 consecutive s
            int b = sb >> 11, si0 = sb & (SEQ - 1);
            for (int ni = 0; ni < 8; ni++) {
                int he = n0 + ni * 16 + l15;
                int h = he >> 6, e = he & 63;
                float bia = bV[he];
                bf16x4 o;
                o[0] = (bf16)(acc[mi][ni][0] + bia);
                o[1] = (bf16)(acc[mi][ni][1] + bia);
                o[2] = (bf16)(acc[mi][ni][2] + bia);
                o[3] = (bf16)(acc[mi][ni][3] + bia);
                *(bf16x4*)&VTb[((size_t)(b * NH + h) * DH + e) * SEQ + si0] = o;
            }
        }
    }
}

// ---------------------------------------------------------------------------
// K2: flash attention, S^T formulation. P stays in registers (S^T C-layout is
// the PV B-operand after pairing frags). No per-iter LDS round-trip.
// Block 512 thr = 8 waves x 16 q-rows = one 128-row q-tile.
// grid (32 bh, 16 y); qt = y<8 ? y : 23-y so CU-paired blocks sum to 17 iters.
// ---------------------------------------------------------------------------
__global__ __launch_bounds__(512, 4) void k_attn(const bf16* __restrict__ Qb,
                                                 const bf16* __restrict__ Kb,
                                                 const bf16* __restrict__ VTb,
                                                 bf16* __restrict__ Zb) {
    int bh = blockIdx.x;
    int y = blockIdx.y;
    int qt = (y < 8) ? y : 23 - y;
    int h = bh & 15, b = bh >> 4;
    __shared__ __align__(16) bf16 Ks[128 * 64];   // K tile [kv][e], swizzled
    __shared__ __align__(16) bf16 Vs[80 * 128];   // V^T tile [e][kv] + ones rows
    int t = threadIdx.x;
    int lane = t & 63, w = t >> 6;
    int l15 = lane & 15, quad = lane >> 4;
    int lrow8 = lane >> 3, lc8 = lane & 7;
    int lrow16 = lane >> 4, lc16 = lane & 15;

    const bf16* qbase = Qb + (size_t)bh * SEQ * DH;
    const bf16* kbase = Kb + (size_t)bh * SEQ * DH;
    const bf16* vbase = VTb + (size_t)bh * DH * SEQ;

    // ones rows 64..79 (row 64 = 1 -> denominator accumulator); row 64 swizzle
    // is identity (64&7==0), rows 65..79 are zeros (swizzle irrelevant).
    if (t < 256) {
        int row = 64 + (t >> 4);
        int c = (t & 15) * 8;
        bf16 v = (row == 64) ? (bf16)1.0f : (bf16)0.0f;
        bf16x8 o = {v, v, v, v, v, v, v, v};
        *(bf16x8*)&Vs[row * 128 + c] = o;
    }

    int qr0 = qt * 128 + w * 16;
    bf16x8 aq[2];   // Q as B-operand: lane holds q=qr0+l15, e=ks*32+quad*8+j
    for (int ks = 0; ks < 2; ks++)
        aq[ks] = *(const bf16x8*)&qbase[(size_t)(qr0 + l15) * DH + ks * 32 + quad * 8];

    const f32x4 z4 = {0.f, 0.f, 0.f, 0.f};
    f32x4 acco[5];   // O^T frags (e-blocks 0..3) + denominator (ones rows)
    for (int no = 0; no < 5; no++) acco[no] = z4;

    for (int kt = 0; kt <= qt; kt++) {
        __syncthreads();
        // stage K tile: rows w*16..w*16+15, swizzled source chunks
        for (int i = 0; i < 2; i++) {
            int row = w * 16 + i * 8 + lrow8;
            int sc = (lc8 ^ (row & 7)) * 8;
            gld16(&Ks[(w * 16 + i * 8) * 64],
                  kbase + (size_t)(kt * 128 + row) * DH + sc);
        }
        // stage V^T tile rows 0..63 (16 chunks/row)
        for (int i = 0; i < 2; i++) {
            int row = i * 32 + w * 4 + lrow16;
            int sc = ((lc16 & 8) | ((lc16 ^ row) & 7)) * 8;
            gld16(&Vs[(i * 32 + w * 4) * 128],
                  vbase + (size_t)row * SEQ + kt * 128 + sc);
        }
        __syncthreads();

        // S^T = K Q^T : lane holds q=l15, kv=ni*16+quad*4+r
        f32x4 accs[8];
        for (int ni = 0; ni < 8; ni++) accs[ni] = z4;
        for (int ks = 0; ks < 2; ks++)
            for (int ni = 0; ni < 8; ni++) {
                bf16x8 ak = frag64(Ks, ni * 16 + l15, ks, quad);
                accs[ni] = MFMA16(ak, aq[ks], accs[ni]);
            }

        if (kt == qt) {   // causal mask on diagonal tile
            int q = qr0 + l15;
            for (int ni = 0; ni < 8; ni++) {
                int kv = kt * 128 + ni * 16 + quad * 4;
                for (int r = 0; r < 4; r++)
                    if (kv + r > q) accs[ni][r] = -1e30f;
            }
        }

        // P^T = exp2(S^T) in registers (B-operand layout for PV)
        bf16x4 pt[8];
        for (int ni = 0; ni < 8; ni++)
            for (int r = 0; r < 4; r++)
                pt[ni][r] = (bf16)EXP2(accs[ni][r]);

        // O^T += V^T(A) x P^T(B), K=32 by pairing frags 2p4, 2p4+1
        for (int p4 = 0; p4 < 4; p4++) {
            bf16x8 bp;
            for (int j = 0; j < 4; j++) {
                bp[j] = pt[2 * p4][j];
                bp[4 + j] = pt[2 * p4 + 1][j];
            }
            int c1 = p4 * 4 + (quad >> 1);
            int c2 = c1 + 2;
            int off = (quad & 1) * 8;    // bytes within chunk
            for (int no = 0; no < 5; no++) {
                int row = no * 16 + l15;
                int ph1 = (c1 & 8) | ((c1 ^ row) & 7);
                int ph2 = (c2 & 8) | ((c2 ^ row) & 7);
                const char* vb = (const char*)Vs + row * 256;
                bf16x4 alo = *(const bf16x4*)(vb + ph1 * 16 + off);
                bf16x4 ahi = *(const bf16x4*)(vb + ph2 * 16 + off);
                bf16x8 av;
                for (int j = 0; j < 4; j++) { av[j] = alo[j]; av[4 + j] = ahi[j]; }
                acco[no] = MFMA16(av, bp, acco[no]);
            }
        }
    }

    // epilogue: denom lives in acco[4][0] of quad 0 lanes (m=0 row)
    float denom = __shfl(acco[4][0], l15, 64);
    float inv = 1.0f / denom;
    int s = qr0 + l15;
    size_t rowbase = ((size_t)b * SEQ + s) * DM + h * DH;
    for (int no = 0; no < 4; no++) {
        bf16x4 o;
        o[0] = (bf16)(acco[no][0] * inv);
        o[1] = (bf16)(acco[no][1] * inv);
        o[2] = (bf16)(acco[no][2] * inv);
        o[3] = (bf16)(acco[no][3] * inv);
        *(bf16x4*)&Zb[rowbase + no * 16 + quad * 4] = o;
    }
}

// ---------------------------------------------------------------------------
// K3: out[s][d] = Zb[s][he] @ woT[d][he] + bO. A=woT (m=d), B=Zb (n=s) so
// stores are packed float4 along d. grid (32 mt, 8 dt), 256 thr.
// ---------------------------------------------------------------------------
__global__ __launch_bounds__(256, 4) void k_out(const bf16* __restrict__ Zb,
                                                const bf16* __restrict__ woT,
                                                const float* __restrict__ bO,
                                                float* __restrict__ out) {
    int mt = blockIdx.x;
    int dt = blockIdx.y;
    __shared__ __align__(16) bf16 Xs[128 * 64];   // Zb rows (s)
    __shared__ __align__(16) bf16 Ws[128 * 64];   // woT rows (d)
    int t = threadIdx.x;
    int lane = t & 63, w = t >> 6;
    int l15 = lane & 15, quad = lane >> 4;
    int lrow = lane >> 3, lc = lane & 7;

    const f32x4 z4 = {0.f, 0.f, 0.f, 0.f};
    f32x4 acc[2][8];
    for (int mi = 0; mi < 2; mi++)
        for (int ni = 0; ni < 8; ni++) acc[mi][ni] = z4;

    int m0 = mt * 128, d0 = dt * 128;
    for (int k0 = 0; k0 < DM; k0 += 64) {
        __syncthreads();
        for (int i = 0; i < 4; i++) {
            int row = w * 32 + i * 8 + lrow;
            int sc = (lc ^ (row & 7)) * 8;
            gld16(&Xs[(w * 32 + i * 8) * 64], Zb + (size_t)(m0 + row) * DM + k0 + sc);
            gld16(&Ws[(w * 32 + i * 8) * 64], woT + (size_t)(d0 + row) * DM + k0 + sc);
        }
        __syncthreads();
        for (int ks = 0; ks < 2; ks++) {
            bf16x8 a0 = frag64(Ws, w * 32 + l15, ks, quad);
            bf16x8 a1 = frag64(Ws, w * 32 + 16 + l15, ks, quad);
            for (int ni = 0; ni < 8; ni++) {
                bf16x8 bfr = frag64(Xs, ni * 16 + l15, ks, quad);
                acc[0][ni] = MFMA16(a0, bfr, acc[0][ni]);
                acc[1][ni] = MFMA16(a1, bfr, acc[1][ni]);
            }
        }
    }
    for (int mi = 0; mi < 2; mi++) {
        int db = d0 + w * 32 + mi * 16 + quad * 4;   // 4 consecutive d
        float4 b4 = *(const float4*)&bO[db];
        for (int ni = 0; ni < 8; ni++) {
            int s = m0 + ni * 16 + l15;
            float4 o;
            o.x = acc[mi][ni][0] + b4.x;
            o.y = acc[mi][ni][1] + b4.y;
            o.z = acc[mi][ni][2] + b4.z;
            o.w = acc[mi][ni][3] + b4.w;
            *(float4*)&out[(size_t)s * DM + db] = o;
        }
    }
}

// ---------------------------------------------------------------------------
extern "C" void kernel_launch(void* const* d_in, const int* in_sizes, int n_in,
                              void* d_out, int out_size, void* d_ws, size_t ws_size,
                              hipStream_t stream) {
    const float* x  = (const float*)d_in[0];
    const float* WQ = (const float*)d_in[1];
    const float* WK = (const float*)d_in[2];
    const float* WV = (const float*)d_in[3];
    const float* WO = (const float*)d_in[4];
    const float* bQ = (const float*)d_in[5];
    const float* bK = (const float*)d_in[6];
    const float* bV = (const float*)d_in[7];
    const float* bO = (const float*)d_in[8];
    float* out = (float*)d_out;

    char* w = (char*)d_ws;
    bf16* xb    = (bf16*)(w + 0);                      //  8 MB
    bf16* wqkvT = (bf16*)(w + (8u << 20));             //  6 MB [p][he=1024][k=1024]
    bf16* woT   = (bf16*)(w + (14u << 20));            //  2 MB [d][he]
    bf16* Qb    = (bf16*)(w + (16u << 20));            //  8 MB [b][h][s][e]
    bf16* Kb    = (bf16*)(w + (24u << 20));            //  8 MB [b][h][s][e]
    bf16* VTb   = (bf16*)(w + (32u << 20));            //  8 MB [b][h][e][s]
    bf16* Zb    = (bf16*)(w + (40u << 20));            //  8 MB [b][s][h*64+e]

    k_cast_x<<<2048, 256, 0, stream>>>(x, xb);
    k_trans_qkv<<<dim3(16, 48), 256, 0, stream>>>(WQ, WK, WV, wqkvT);
    k_trans_wo<<<dim3(16, 16), 256, 0, stream>>>(WO, woT);
    k_qkv<<<dim3(32, 8, 3), 256, 0, stream>>>(xb, wqkvT, bQ, bK, bV, Qb, Kb, VTb);
    k_attn<<<dim3(32, 16), 512, 0, stream>>>(Qb, Kb, VTb, Zb);
    k_out<<<dim3(32, 8), 256, 0, stream>>>(Zb, woT, bO, out);
}